// Round 1
// baseline (139.478 us; speedup 1.0000x reference)
//
#include <hip/hip_runtime.h>
#include <math.h>

#define N_IMG 32
#define IMG_W 1024
#define IMG_HW (1024 * 1024)
#define P_PTS 16
#define BPI 256   // blocks per image
#define TPB 256   // threads per block

// acc layout: acc[img*4 + {0:sum(p*t), 1:sum(p), 2:sum(t), 3:sum(focal)}]

__global__ __launch_bounds__(TPB) void ImageMaskPointLoss_main(
    const float* __restrict__ pred,
    const float* __restrict__ gt,
    float* __restrict__ acc) {
    const int img = blockIdx.x / BPI;
    const int blk = blockIdx.x % BPI;

    const float4* __restrict__ p4 = (const float4*)(pred + (size_t)img * IMG_HW);
    const float4* __restrict__ g4 = (const float4*)(gt + (size_t)img * IMG_HW);

    // IMG_HW/4 = 262144 float4 per image; / BPI = 1024 per block; / TPB = 4 per thread
    float s_pt = 0.f, s_p = 0.f, s_t = 0.f, s_f = 0.f;
    const int base = blk * (IMG_HW / 4 / BPI) + threadIdx.x;
#pragma unroll
    for (int i = 0; i < (IMG_HW / 4 / BPI / TPB); ++i) {
        float4 z4 = p4[base + i * TPB];
        float4 t4 = g4[base + i * TPB];
        float zz[4] = {z4.x, z4.y, z4.z, z4.w};
        float tt[4] = {t4.x, t4.y, t4.z, t4.w};
#pragma unroll
        for (int j = 0; j < 4; ++j) {
            float z = zz[j], t = tt[j];
            float p = 1.f / (1.f + __expf(-z));
            s_p += p;
            s_t += t;
            s_pt += p * t;
            // stable BCE with logits: max(z,0) - z*t + log1p(exp(-|z|))
            float ce = fmaxf(z, 0.f) - z * t + log1pf(__expf(-fabsf(z)));
            float p_t = p * t + (1.f - p) * (1.f - t);
            float omp = 1.f - p_t;
            float alpha_t = 0.25f * t + 0.75f * (1.f - t);
            s_f += alpha_t * ce * omp * omp;
        }
    }

    // block reduction: wave64 shuffle, then 4 waves via LDS
    __shared__ float sm[4][TPB / 64];
    const int wid = threadIdx.x >> 6;
    const int lane = threadIdx.x & 63;
    float vals[4] = {s_pt, s_p, s_t, s_f};
#pragma unroll
    for (int k = 0; k < 4; ++k) {
        float v = vals[k];
#pragma unroll
        for (int off = 32; off > 0; off >>= 1) v += __shfl_down(v, off, 64);
        if (lane == 0) sm[k][wid] = v;
    }
    __syncthreads();
    if (threadIdx.x < 4) {
        float v = 0.f;
#pragma unroll
        for (int w = 0; w < TPB / 64; ++w) v += sm[threadIdx.x][w];
        atomicAdd(&acc[img * 4 + threadIdx.x], v);
    }
}

__global__ __launch_bounds__(TPB) void ImageMaskPointLoss_finalize(
    const float* __restrict__ acc,
    const float* __restrict__ pred,
    const int* __restrict__ pos,
    const int* __restrict__ neg,
    float* __restrict__ out) {
    float contrib = 0.f;

    // dice + focal per image (threads 0..31)
    if (threadIdx.x < N_IMG) {
        float spt = acc[threadIdx.x * 4 + 0];
        float sp = acc[threadIdx.x * 4 + 1];
        float st = acc[threadIdx.x * 4 + 2];
        float sf = acc[threadIdx.x * 4 + 3];
        float dice_i = 1.f - (2.f * spt + 1.f) / (sp + st + 1.f);
        contrib += dice_i / (float)N_IMG;                         // mean over images
        contrib += sf / ((float)N_IMG * (float)IMG_HW);           // global focal mean
    }

    // point loss: 512 pos + 512 neg gathers
    const int npts = N_IMG * P_PTS;  // 512
    for (int idx = threadIdx.x; idx < 2 * npts; idx += TPB) {
        bool is_pos = idx < npts;
        int k = is_pos ? idx : idx - npts;
        const int* arr = is_pos ? pos : neg;
        int x = arr[k * 2 + 0];
        int y = arr[k * 2 + 1];
        int n = k / P_PTS;
        float z = pred[(size_t)n * IMG_HW + (size_t)y * IMG_W + x];
        // pos: softplus(-z), neg: softplus(z); softplus(a) = max(a,0)+log1p(exp(-|a|))
        float a = is_pos ? -z : z;
        float sp = fmaxf(a, 0.f) + log1pf(__expf(-fabsf(a)));
        contrib += sp / (float)N_IMG;
    }

    // block reduce contrib
    __shared__ float sm[TPB / 64];
    const int wid = threadIdx.x >> 6;
    const int lane = threadIdx.x & 63;
#pragma unroll
    for (int off = 32; off > 0; off >>= 1) contrib += __shfl_down(contrib, off, 64);
    if (lane == 0) sm[wid] = contrib;
    __syncthreads();
    if (threadIdx.x == 0) {
        float tot = 0.f;
#pragma unroll
        for (int w = 0; w < TPB / 64; ++w) tot += sm[w];
        out[0] = tot;
    }
}

extern "C" void kernel_launch(void* const* d_in, const int* in_sizes, int n_in,
                              void* d_out, int out_size, void* d_ws, size_t ws_size,
                              hipStream_t stream) {
    const float* pred = (const float*)d_in[0];
    const float* gt = (const float*)d_in[1];
    const int* pos = (const int*)d_in[2];
    const int* neg = (const int*)d_in[3];
    float* out = (float*)d_out;
    float* acc = (float*)d_ws;

    hipMemsetAsync(acc, 0, N_IMG * 4 * sizeof(float), stream);
    ImageMaskPointLoss_main<<<N_IMG * BPI, TPB, 0, stream>>>(pred, gt, acc);
    ImageMaskPointLoss_finalize<<<1, TPB, 0, stream>>>(acc, pred, pos, neg, out);
}

// Round 3
// 71.651 us; speedup vs baseline: 1.9466x; 1.9466x over previous
//
#include <hip/hip_runtime.h>
#include <math.h>

#define N_IMG 32
#define IMG_W 1024
#define IMG_HW (1024 * 1024)
#define P_PTS 16
#define BPI 256   // blocks per image
#define TPB 256   // threads per block

// acc layout: acc[img*4 + {0:sum(p*t), 1:sum(p), 2:sum(t), 3:sum(focal)}]

__global__ __launch_bounds__(TPB) void ImageMaskPointLoss_main(
    const float* __restrict__ pred,
    const float* __restrict__ gt,
    float* __restrict__ acc) {
    const int img = blockIdx.x / BPI;
    const int blk = blockIdx.x % BPI;

    const float4* __restrict__ p4 = (const float4*)(pred + (size_t)img * IMG_HW);
    const float4* __restrict__ g4 = (const float4*)(gt + (size_t)img * IMG_HW);

    // IMG_HW/4 = 262144 float4 per image; / BPI = 1024 per block; / TPB = 4 per thread
    float s_pt = 0.f, s_p = 0.f, s_t = 0.f, s_f = 0.f;
    const int base = blk * (IMG_HW / 4 / BPI) + threadIdx.x;
#pragma unroll
    for (int i = 0; i < (IMG_HW / 4 / BPI / TPB); ++i) {
        float4 z4 = p4[base + i * TPB];
        float4 t4 = g4[base + i * TPB];
        float zz[4] = {z4.x, z4.y, z4.z, z4.w};
        float tt[4] = {t4.x, t4.y, t4.z, t4.w};
#pragma unroll
        for (int j = 0; j < 4; ++j) {
            float z = zz[j], t = tt[j];
            // t is exactly 0.0 or 1.0 (round of uniform)
            float az = fabsf(z);
            float e = __builtin_amdgcn_exp2f(az * -1.442695041f);  // exp(-|z|)  [v_mul + v_exp]
            float d = 1.f + e;
            float r = __builtin_amdgcn_rcpf(d);       // 1/(1+e)    [v_rcp]
            float er = e * r;                         // == 1 - r in this algebra
            float L = 0.693147181f * __builtin_amdgcn_logf(d);  // log1p(e)  [v_log + v_mul]

            bool zpos = z >= 0.f;
            bool tb = t > 0.5f;
            float p = zpos ? r : er;                  // sigmoid(z)
            s_p += p;
            s_t += t;
            s_pt = fmaf(p, t, s_pt);

            // ce = softplus(z) - z*t = max(a,0) + log1p(exp(-|z|)), a = t ? -z : z
            float m = fmaxf(tb ? -z : z, 0.f);
            float ce = m + L;
            // q = 1 - p_t:  p_t = tb ? p : 1-p  ->  q = (tb != zpos) ? r : er
            float q = (tb != zpos) ? r : er;
            float alpha = tb ? 0.25f : 0.75f;
            s_f = fmaf(alpha * ce, q * q, s_f);
        }
    }

    // block reduction: wave64 shuffle, then 4 waves via LDS
    __shared__ float sm[4][TPB / 64];
    const int wid = threadIdx.x >> 6;
    const int lane = threadIdx.x & 63;
    float vals[4] = {s_pt, s_p, s_t, s_f};
#pragma unroll
    for (int k = 0; k < 4; ++k) {
        float v = vals[k];
#pragma unroll
        for (int off = 32; off > 0; off >>= 1) v += __shfl_down(v, off, 64);
        if (lane == 0) sm[k][wid] = v;
    }
    __syncthreads();
    if (threadIdx.x < 4) {
        float v = 0.f;
#pragma unroll
        for (int w = 0; w < TPB / 64; ++w) v += sm[threadIdx.x][w];
        atomicAdd(&acc[img * 4 + threadIdx.x], v);
    }
}

__global__ __launch_bounds__(TPB) void ImageMaskPointLoss_finalize(
    const float* __restrict__ acc,
    const float* __restrict__ pred,
    const int* __restrict__ pos,
    const int* __restrict__ neg,
    float* __restrict__ out) {
    float contrib = 0.f;

    // dice + focal per image (threads 0..31)
    if (threadIdx.x < N_IMG) {
        float spt = acc[threadIdx.x * 4 + 0];
        float sp = acc[threadIdx.x * 4 + 1];
        float st = acc[threadIdx.x * 4 + 2];
        float sf = acc[threadIdx.x * 4 + 3];
        float dice_i = 1.f - (2.f * spt + 1.f) / (sp + st + 1.f);
        contrib += dice_i / (float)N_IMG;                         // mean over images
        contrib += sf / ((float)N_IMG * (float)IMG_HW);           // global focal mean
    }

    // point loss: 512 pos + 512 neg gathers
    const int npts = N_IMG * P_PTS;  // 512
    for (int idx = threadIdx.x; idx < 2 * npts; idx += TPB) {
        bool is_pos = idx < npts;
        int k = is_pos ? idx : idx - npts;
        const int* arr = is_pos ? pos : neg;
        int x = arr[k * 2 + 0];
        int y = arr[k * 2 + 1];
        int n = k / P_PTS;
        float z = pred[(size_t)n * IMG_HW + (size_t)y * IMG_W + x];
        // pos: softplus(-z), neg: softplus(z); softplus(a) = max(a,0)+log1p(exp(-|a|))
        float a = is_pos ? -z : z;
        float e = __builtin_amdgcn_exp2f(fabsf(a) * -1.442695041f);
        float sp = fmaxf(a, 0.f) + 0.693147181f * __builtin_amdgcn_logf(1.f + e);
        contrib += sp / (float)N_IMG;
    }

    // block reduce contrib
    __shared__ float sm[TPB / 64];
    const int wid = threadIdx.x >> 6;
    const int lane = threadIdx.x & 63;
#pragma unroll
    for (int off = 32; off > 0; off >>= 1) contrib += __shfl_down(contrib, off, 64);
    if (lane == 0) sm[wid] = contrib;
    __syncthreads();
    if (threadIdx.x == 0) {
        float tot = 0.f;
#pragma unroll
        for (int w = 0; w < TPB / 64; ++w) tot += sm[w];
        out[0] = tot;
    }
}

extern "C" void kernel_launch(void* const* d_in, const int* in_sizes, int n_in,
                              void* d_out, int out_size, void* d_ws, size_t ws_size,
                              hipStream_t stream) {
    const float* pred = (const float*)d_in[0];
    const float* gt = (const float*)d_in[1];
    const int* pos = (const int*)d_in[2];
    const int* neg = (const int*)d_in[3];
    float* out = (float*)d_out;
    float* acc = (float*)d_ws;

    (void)hipMemsetAsync(acc, 0, N_IMG * 4 * sizeof(float), stream);
    ImageMaskPointLoss_main<<<N_IMG * BPI, TPB, 0, stream>>>(pred, gt, acc);
    ImageMaskPointLoss_finalize<<<1, TPB, 0, stream>>>(acc, pred, pos, neg, out);
}